// Round 9
// baseline (221.782 us; speedup 1.0000x reference)
//
#include <hip/hip_runtime.h>

// Problem constants (fixed by setup_inputs)
#define BB 2
#define CC 256
#define HH 100
#define WW 100
#define NROI 512
#define KDIM 12544   // 49*256
#define FC 1024

typedef _Float16 half_t;
typedef _Float16 f16x2 __attribute__((ext_vector_type(2)));
typedef _Float16 f16x8 __attribute__((ext_vector_type(8)));
typedef _Float16 f16x4 __attribute__((ext_vector_type(4)));
typedef float f32x4 __attribute__((ext_vector_type(4)));

// async global->LDS DMA, 16B per lane, wave-uniform LDS base + lane*16
__device__ __forceinline__ void gload16(const half_t* g, half_t* l) {
  __builtin_amdgcn_global_load_lds(
      (const __attribute__((address_space(1))) unsigned int*)g,
      (__attribute__((address_space(3))) unsigned int*)l, 16, 0, 0);
}

// ---------------- fused prep: w1/w2 fp32->fp16 converts + feat transpose ----------------
__global__ __launch_bounds__(256) void prep(const float* __restrict__ feat,
                                            half_t* __restrict__ featT,
                                            const float* __restrict__ w1,
                                            half_t* __restrict__ w1h,
                                            const float* __restrict__ w2,
                                            half_t* __restrict__ w2h) {
  int bid = blockIdx.x;
  if (bid < 12544) {                       // w1: FC*KDIM = 12,845,056 elems
    int i4 = (bid * 256 + threadIdx.x) * 4;
    float4 v = *(const float4*)(w1 + i4);
    f16x4 o;
    o[0] = (half_t)v.x; o[1] = (half_t)v.y; o[2] = (half_t)v.z; o[3] = (half_t)v.w;
    *(f16x4*)(w1h + i4) = o;
    return;
  }
  bid -= 12544;
  if (bid < 1024) {                        // w2: FC*FC = 1,048,576 elems
    int i4 = (bid * 256 + threadIdx.x) * 4;
    float4 v = *(const float4*)(w2 + i4);
    f16x4 o;
    o[0] = (half_t)v.x; o[1] = (half_t)v.y; o[2] = (half_t)v.z; o[3] = (half_t)v.w;
    *(f16x4*)(w2h + i4) = o;
    return;
  }
  bid -= 1024;                             // transpose: 313*8*2 = 5008 blocks
  __shared__ float tile[32][33];
  const int bx = bid % 313;
  const int rem = bid / 313;
  const int by = rem & 7;
  const int bz = rem >> 3;
  const int tx = threadIdx.x & 31, ty = threadIdx.x >> 5;
  const int hw0 = bx * 32;
  const int c0 = by * 32;
  const float* fb = feat + (size_t)bz * CC * (HH * WW);
#pragma unroll
  for (int i = 0; i < 4; i++) {
    int c = c0 + ty + i * 8;
    int hw = hw0 + tx;
    tile[ty + i * 8][tx] = (hw < HH * WW) ? fb[(size_t)c * (HH * WW) + hw] : 0.0f;
  }
  __syncthreads();
  half_t* ob = featT + (size_t)bz * (HH * WW) * CC;
#pragma unroll
  for (int i = 0; i < 4; i++) {
    int hw = hw0 + ty + i * 8;
    int c = c0 + tx;
    if (hw < HH * WW) ob[(size_t)hw * CC + c] = (half_t)tile[tx][ty + i * 8];
  }
}

// ---------------- deformable PSROI pooling, one block (512 thr) per ROI ----------------
// PASS2: om = split-K partials part3[z][n][147]; z-reduce + b3 folded into phase 1.
// Phase 2: lane = (pixel-half, 8 channels); 8 pair-gathers (16 pixels) in flight.
struct PixW { int idx; float w; };

template <bool PASS2>
__global__ __launch_bounds__(512) void pool_kernel(const half_t* __restrict__ featT,
                                                   const float* __restrict__ rois,
                                                   const float* __restrict__ part3,
                                                   const float* __restrict__ b3,
                                                   half_t* __restrict__ xout,
                                                   float* __restrict__ out) {
  __shared__ __align__(16) PixW s_pix[49 * 32];       // <=25 pixels, pad to x16
  __shared__ int s_cnt[49];
  __shared__ float s_scale[49];
  __shared__ float  s_outf[PASS2 ? KDIM : 1];
  __shared__ half_t s_outh[PASS2 ? 1 : KDIM];

  const int n = blockIdx.x;
  const int tid = threadIdx.x;
  const float* r = rois + n * 5;
  const int b = (int)r[0];
  const float rsw = rintf(r[1]) * 0.0625f - 0.5f;
  const float rsh = rintf(r[2]) * 0.0625f - 0.5f;
  const float rew = (rintf(r[3]) + 1.0f) * 0.0625f - 0.5f;
  const float reh = (rintf(r[4]) + 1.0f) * 0.0625f - 0.5f;
  const float roi_w = fmaxf(rew - rsw, 0.1f);
  const float roi_h = fmaxf(reh - rsh, 0.1f);
  const float bin_h = roi_h / 7.0f, bin_w = roi_w / 7.0f;
  const float sub_h = bin_h * 0.25f, sub_w = bin_w * 0.25f;
  const half_t* fb = featT + (size_t)b * (HH * WW) * CC;

  if (tid < 49) {
    const int p = tid, ph = p / 7, pw = p - ph * 7;
    float tx = 0.0f, ty = 0.0f, mask = 1.0f;
    if (PASS2) {
      float o0 = b3[p], o1 = b3[49 + p], o2 = b3[98 + p];
#pragma unroll
      for (int zz = 0; zz < 8; zz++) {
        const float* pz = part3 + ((size_t)zz * NROI + n) * 147;
        o0 += pz[p]; o1 += pz[49 + p]; o2 += pz[98 + p];
      }
      tx = o0 * 0.1f;
      ty = o1 * 0.1f;
      mask = 1.0f / (1.0f + expf(-o2));
    }
    const float hst = (float)ph * bin_h + rsh + ty * roi_h;
    const float wst = (float)pw * bin_w + rsw + tx * roi_w;
    float wh[6] = {0, 0, 0, 0, 0, 0};
    float hc0 = fminf(fmaxf(hst, 0.0f), 99.0f);
    const int r0 = (int)hc0;
    int rtop = r0;
    float vsh = 0.0f;
#pragma unroll
    for (int i = 0; i < 4; i++) {
      float h = hst + (float)i * sub_h;
      bool v = (h >= -0.5f) && (h <= (float)HH - 0.5f);
      float hc = fminf(fmaxf(h, 0.0f), 99.0f);
      int h0 = (int)hc;
      float lh = hc - (float)h0;
      int h1 = min(h0 + 1, HH - 1);
      if (v) { wh[h0 - r0] += 1.0f - lh; wh[h1 - r0] += lh; vsh += 1.0f; }
      rtop = h1;
    }
    float wwc[6] = {0, 0, 0, 0, 0, 0};
    float wc0 = fminf(fmaxf(wst, 0.0f), 99.0f);
    const int c0 = (int)wc0;
    int ctop = c0;
    float vsw = 0.0f;
#pragma unroll
    for (int j = 0; j < 4; j++) {
      float w = wst + (float)j * sub_w;
      bool v = (w >= -0.5f) && (w <= (float)WW - 0.5f);
      float wc = fminf(fmaxf(w, 0.0f), 99.0f);
      int w0 = (int)wc;
      float lw = wc - (float)w0;
      int w1 = min(w0 + 1, WW - 1);
      if (v) { wwc[w0 - c0] += 1.0f - lw; wwc[w1 - c0] += lw; vsw += 1.0f; }
      ctop = w1;
    }
    const int nr = rtop - r0 + 1, nc = ctop - c0 + 1;
    float cntf = vsh * vsw;
    s_scale[p] = (cntf > 0.0f) ? mask / cntf : 0.0f;
    PixW* dst = &s_pix[p * 32];
    int m = 0;
    for (int ri = 0; ri < nr; ri++) {
      int rowoff = (r0 + ri) * WW + c0;
      for (int ci = 0; ci < nc; ci++) {
        dst[m].idx = (rowoff + ci) * CC;
        dst[m].w = wh[ri] * wwc[ci];
        m++;
      }
    }
    while (m & 15) { dst[m].idx = 0; dst[m].w = 0.0f; m++; }   // pad to mult of 16
    s_cnt[p] = m;
  }
  __syncthreads();

  // ---- phase 2: wave per bin; lane = (pixel-half, 8 channels); 8 pair-gathers in flight ----
  const int wv = tid >> 6;
  const int lane = tid & 63;
  const int half = lane >> 5;              // 0: even pixel, 1: odd pixel
  const int c8 = (lane & 31) * 8;          // 8 channels per lane, 32 lanes = 256 ch
  for (int p = wv; p < 49; p += 8) {
    const int cnt = s_cnt[p];              // wave-uniform LDS read
    const PixW* cp = &s_pix[p * 32];
    float a0 = 0, a1 = 0, a2 = 0, a3 = 0, a4 = 0, a5 = 0, a6 = 0, a7 = 0;
    for (int q = 0; q < cnt; q += 16) {
      PixW e0 = cp[q + 0 + half];          // 2-way broadcast (free)
      PixW e1 = cp[q + 2 + half];
      PixW e2 = cp[q + 4 + half];
      PixW e3 = cp[q + 6 + half];
      PixW e4 = cp[q + 8 + half];
      PixW e5 = cp[q + 10 + half];
      PixW e6 = cp[q + 12 + half];
      PixW e7 = cp[q + 14 + half];
      f16x8 v0 = *(const f16x8*)(fb + e0.idx + c8);
      f16x8 v1 = *(const f16x8*)(fb + e1.idx + c8);
      f16x8 v2 = *(const f16x8*)(fb + e2.idx + c8);
      f16x8 v3 = *(const f16x8*)(fb + e3.idx + c8);
      f16x8 v4 = *(const f16x8*)(fb + e4.idx + c8);
      f16x8 v5 = *(const f16x8*)(fb + e5.idx + c8);
      f16x8 v6 = *(const f16x8*)(fb + e6.idx + c8);
      f16x8 v7 = *(const f16x8*)(fb + e7.idx + c8);
      a0 += e0.w * (float)v0[0] + e1.w * (float)v1[0] + e2.w * (float)v2[0] + e3.w * (float)v3[0]
          + e4.w * (float)v4[0] + e5.w * (float)v5[0] + e6.w * (float)v6[0] + e7.w * (float)v7[0];
      a1 += e0.w * (float)v0[1] + e1.w * (float)v1[1] + e2.w * (float)v2[1] + e3.w * (float)v3[1]
          + e4.w * (float)v4[1] + e5.w * (float)v5[1] + e6.w * (float)v6[1] + e7.w * (float)v7[1];
      a2 += e0.w * (float)v0[2] + e1.w * (float)v1[2] + e2.w * (float)v2[2] + e3.w * (float)v3[2]
          + e4.w * (float)v4[2] + e5.w * (float)v5[2] + e6.w * (float)v6[2] + e7.w * (float)v7[2];
      a3 += e0.w * (float)v0[3] + e1.w * (float)v1[3] + e2.w * (float)v2[3] + e3.w * (float)v3[3]
          + e4.w * (float)v4[3] + e5.w * (float)v5[3] + e6.w * (float)v6[3] + e7.w * (float)v7[3];
      a4 += e0.w * (float)v0[4] + e1.w * (float)v1[4] + e2.w * (float)v2[4] + e3.w * (float)v3[4]
          + e4.w * (float)v4[4] + e5.w * (float)v5[4] + e6.w * (float)v6[4] + e7.w * (float)v7[4];
      a5 += e0.w * (float)v0[5] + e1.w * (float)v1[5] + e2.w * (float)v2[5] + e3.w * (float)v3[5]
          + e4.w * (float)v4[5] + e5.w * (float)v5[5] + e6.w * (float)v6[5] + e7.w * (float)v7[5];
      a6 += e0.w * (float)v0[6] + e1.w * (float)v1[6] + e2.w * (float)v2[6] + e3.w * (float)v3[6]
          + e4.w * (float)v4[6] + e5.w * (float)v5[6] + e6.w * (float)v6[6] + e7.w * (float)v7[6];
      a7 += e0.w * (float)v0[7] + e1.w * (float)v1[7] + e2.w * (float)v2[7] + e3.w * (float)v3[7]
          + e4.w * (float)v4[7] + e5.w * (float)v5[7] + e6.w * (float)v6[7] + e7.w * (float)v7[7];
    }
    // combine even/odd pixel halves (lanes l and l+32 hold same channels)
    a0 += __shfl_xor(a0, 32); a1 += __shfl_xor(a1, 32);
    a2 += __shfl_xor(a2, 32); a3 += __shfl_xor(a3, 32);
    a4 += __shfl_xor(a4, 32); a5 += __shfl_xor(a5, 32);
    a6 += __shfl_xor(a6, 32); a7 += __shfl_xor(a7, 32);
    if (half == 0) {
      float sc = s_scale[p];
      a0 *= sc; a1 *= sc; a2 *= sc; a3 *= sc; a4 *= sc; a5 *= sc; a6 *= sc; a7 *= sc;
      if (PASS2) {
        s_outf[(c8 + 0) * 49 + p] = a0;
        s_outf[(c8 + 1) * 49 + p] = a1;
        s_outf[(c8 + 2) * 49 + p] = a2;
        s_outf[(c8 + 3) * 49 + p] = a3;
        s_outf[(c8 + 4) * 49 + p] = a4;
        s_outf[(c8 + 5) * 49 + p] = a5;
        s_outf[(c8 + 6) * 49 + p] = a6;
        s_outf[(c8 + 7) * 49 + p] = a7;
      } else {
        s_outh[(c8 + 0) * 49 + p] = (half_t)a0;
        s_outh[(c8 + 1) * 49 + p] = (half_t)a1;
        s_outh[(c8 + 2) * 49 + p] = (half_t)a2;
        s_outh[(c8 + 3) * 49 + p] = (half_t)a3;
        s_outh[(c8 + 4) * 49 + p] = (half_t)a4;
        s_outh[(c8 + 5) * 49 + p] = (half_t)a5;
        s_outh[(c8 + 6) * 49 + p] = (half_t)a6;
        s_outh[(c8 + 7) * 49 + p] = (half_t)a7;
      }
    }
  }
  __syncthreads();

  if (PASS2) {
    float* ob = out + (size_t)n * KDIM;
    for (int l = tid * 4; l < KDIM; l += 2048)
      *(float4*)(ob + l) = *(const float4*)(s_outf + l);
  } else {
    half_t* ob = xout + (size_t)n * KDIM;
    for (int l = tid * 8; l < KDIM; l += 4096)
      *(f16x8*)(ob + l) = *(const f16x8*)(s_outh + l);
  }
}

// ---- GEMM1: 256(M)x128(N) tile, 512 thr / 8 waves (4M x 2N of 64x64), BK=64 ----
// T3/T4: global_load_lds + counted vmcnt(6), double-buffered LDS (96 KB, 1 block/CU,
// same 8 waves/CU as the 128x128 variant). Logical traffic 205 -> 154 MB vs 128x128.
// Source-side bank swizzle; XCD z-grouping. Grid (2,8,SK) = 16*SK blocks.
// P layout: [z][tile=by*2+bx][wave 0..7][q=(i*4+j)*4+rr][lane]
template <int SK>
__global__ __launch_bounds__(512, 1) void gemm_lds_w(const half_t* __restrict__ A,
                                                     const half_t* __restrict__ B,
                                                     float* __restrict__ P, int K) {
  __shared__ half_t As[2][256 * 64];   // 64 KB
  __shared__ half_t Bs[2][128 * 64];   // 32 KB
  const int d = blockIdx.x + gridDim.x * (blockIdx.y + gridDim.y * blockIdx.z);
  const int g = (d & 7) * (SK * 2) + (d >> 3);   // bijective: 16*SK blocks, %8==0
  const int z = g >> 4;          // 16 tiles per z-slice
  const int tile = g & 15;
  const int m0 = (tile & 1) * 256;
  const int n0 = (tile >> 1) * 128;
  const int Kc = K / SK;
  const int kbeg = z * Kc;
  const int tid = threadIdx.x;
  const int lane = tid & 63;
  const int wave = tid >> 6;              // 0..7
  const int wm = (wave & 3) * 64;         // 4 M-waves
  const int wn = (wave >> 2) * 64;        // 2 N-waves
  const int fr = lane & 15;
  const int kc0 = lane >> 4;              // 0..3
  // staging: wave owns A rows [wave*32, +32), B rows [wave*16, +16); 8 rows per call
  const int lr = lane >> 3;               // 0..7
  const int lc = (lane & 7) ^ lr;         // pre-swizzled global 16B-chunk
  const half_t* Ag = A + (size_t)(m0 + wave * 32 + lr) * K + kbeg + lc * 8;
  const half_t* Bg = B + (size_t)(n0 + wave * 16 + lr) * K + kbeg + lc * 8;
  f32x4 acc[4][4] = {};

  auto stage = [&](int buf, int ko) {     // 6 DMAs per wave
#pragma unroll
    for (int s = 0; s < 4; s++)
      gload16(Ag + (size_t)(8 * s) * K + ko, &As[buf][wave * 2048 + s * 512]);
#pragma unroll
    for (int s = 0; s < 2; s++)
      gload16(Bg + (size_t)(8 * s) * K + ko, &Bs[buf][wave * 1024 + s * 512]);
  };

  const int iters = Kc >> 6;
  stage(0, 0);
  if (iters > 1) {
    stage(1, 64);
    asm volatile("s_waitcnt vmcnt(6)" ::: "memory");   // buf0 complete, buf1 in flight
  } else {
    asm volatile("s_waitcnt vmcnt(0)" ::: "memory");
  }
  __builtin_amdgcn_s_barrier();

  for (int it = 0; it < iters; it++) {
    const int cur = it & 1;
#pragma unroll
    for (int ks = 0; ks < 2; ks++) {
      const int swz = ((kc0 + ks * 4) ^ (fr & 7)) * 8;
      f16x8 af[4], bf[4];
#pragma unroll
      for (int i = 0; i < 4; i++) af[i] = *(const f16x8*)&As[cur][(wm + i * 16 + fr) * 64 + swz];
#pragma unroll
      for (int j = 0; j < 4; j++) bf[j] = *(const f16x8*)&Bs[cur][(wn + j * 16 + fr) * 64 + swz];
      __builtin_amdgcn_s_setprio(1);
#pragma unroll
      for (int i = 0; i < 4; i++)
#pragma unroll
        for (int j = 0; j < 4; j++)
          acc[i][j] = __builtin_amdgcn_mfma_f32_16x16x32_f16(af[i], bf[j], acc[i][j], 0, 0, 0);
      __builtin_amdgcn_s_setprio(0);
    }
    asm volatile("s_waitcnt lgkmcnt(0)" ::: "memory");
    __builtin_amdgcn_s_barrier();
    const bool issue = (it + 2 < iters);
    if (issue) stage(cur, (it + 2) * 64);
    if (it + 1 < iters) {
      if (issue) asm volatile("s_waitcnt vmcnt(6)" ::: "memory");
      else       asm volatile("s_waitcnt vmcnt(0)" ::: "memory");
      __builtin_amdgcn_s_barrier();
    }
  }
  float* Pz = P + (((size_t)z * 16 + tile) * 8 + wave) * 4096;
#pragma unroll
  for (int i = 0; i < 4; i++)
#pragma unroll
    for (int j = 0; j < 4; j++)
#pragma unroll
      for (int rr = 0; rr < 4; rr++)
        Pz[((i * 4 + j) * 4 + rr) * 64 + lane] = acc[i][j][rr];
}

// ---- reduce for gemm_lds_w layout: lane0(6) q(6) wave(3) tile(4) ----
template <bool OUT16, bool RELU, int SK>
__global__ __launch_bounds__(256) void reduce_w(const float* __restrict__ P,
                                                const float* __restrict__ bias,
                                                void* __restrict__ out,
                                                int MN, int N) {
  int i4 = (blockIdx.x * 256 + threadIdx.x) * 4;
  if (i4 >= MN) return;
  float4 s = *(const float4*)(P + i4);
#pragma unroll
  for (int z = 1; z < SK; z++) {
    float4 t = *(const float4*)(P + (size_t)z * MN + i4);
    s.x += t.x; s.y += t.y; s.z += t.z; s.w += t.w;
  }
  const int lane0 = i4 & 63;
  const int q     = (i4 >> 6) & 63;
  const int wave  = (i4 >> 12) & 7;
  const int tile  = (i4 >> 15) & 15;
  const int rr = q & 3, j_ = (q >> 2) & 3, i_ = q >> 4;
  const int row = (tile & 1) * 256 + (wave & 3) * 64 + i_ * 16 + (lane0 >> 4) * 4 + rr;
  const int col = (tile >> 1) * 128 + (wave >> 2) * 64 + j_ * 16 + (lane0 & 15);
  float4 bv = *(const float4*)(bias + col);
  s.x += bv.x; s.y += bv.y; s.z += bv.z; s.w += bv.w;
  if (RELU) {
    s.x = fmaxf(s.x, 0.0f); s.y = fmaxf(s.y, 0.0f);
    s.z = fmaxf(s.z, 0.0f); s.w = fmaxf(s.w, 0.0f);
  }
  size_t o = (size_t)row * N + col;
  if (OUT16) {
    f16x4 ov;
    ov[0] = (half_t)s.x; ov[1] = (half_t)s.y; ov[2] = (half_t)s.z; ov[3] = (half_t)s.w;
    *(f16x4*)((half_t*)out + o) = ov;
  } else {
    *(float4*)((float*)out + o) = s;
  }
}

// ---- GEMM2: split-K fp16 MFMA, 128x128 tile, 256 thr (proven T3/T4 structure) ----
// P layout: [z][tile=by*4+bx][wave 0..3][q][lane]
template <int SK>
__global__ __launch_bounds__(256, 2) void gemm_lds(const half_t* __restrict__ A,
                                                   const half_t* __restrict__ B,
                                                   float* __restrict__ P, int K) {
  __shared__ half_t As[2][128 * 64];   // 32 KB
  __shared__ half_t Bs[2][128 * 64];   // 32 KB
  const int d = blockIdx.x + gridDim.x * (blockIdx.y + gridDim.y * blockIdx.z);
  const int g = (d & 7) * (SK * 4) + (d >> 3);   // bijective: 32*SK blocks, %8==0
  const int z = g >> 5;
  const int tile = g & 31;
  const int m0 = (tile & 3) * 128;
  const int n0 = (tile >> 2) * 128;
  const int Kc = K / SK;
  const int kbeg = z * Kc;
  const int tid = threadIdx.x;
  const int lane = tid & 63;
  const int wave = tid >> 6;
  const int wm = (wave & 1) * 64;
  const int wn = (wave >> 1) * 64;
  const int fr = lane & 15;
  const int kc0 = lane >> 4;
  const int lr = lane >> 3;
  const int lc = (lane & 7) ^ lr;
  const half_t* Ag = A + (size_t)(m0 + wave * 8 + lr) * K + kbeg + lc * 8;
  const half_t* Bg = B + (size_t)(n0 + wave * 8 + lr) * K + kbeg + lc * 8;
  f32x4 acc[4][4] = {};

  auto stage = [&](int buf, int ko) {
#pragma unroll
    for (int s = 0; s < 4; s++)
      gload16(Ag + (size_t)(32 * s) * K + ko, &As[buf][s * 2048 + wave * 512]);
#pragma unroll
    for (int s = 0; s < 4; s++)
      gload16(Bg + (size_t)(32 * s) * K + ko, &Bs[buf][s * 2048 + wave * 512]);
  };

  const int iters = Kc >> 6;
  stage(0, 0);
  if (iters > 1) {
    stage(1, 64);
    asm volatile("s_waitcnt vmcnt(8)" ::: "memory");
  } else {
    asm volatile("s_waitcnt vmcnt(0)" ::: "memory");
  }
  __builtin_amdgcn_s_barrier();

  for (int it = 0; it < iters; it++) {
    const int cur = it & 1;
#pragma unroll
    for (int ks = 0; ks < 2; ks++) {
      const int swz = ((kc0 + ks * 4) ^ (fr & 7)) * 8;
      f16x8 af[4], bf[4];
#pragma unroll
      for (int i = 0; i < 4; i++) af[i] = *(const f16x8*)&As[cur][(wm + i * 16 + fr) * 64 + swz];
#pragma unroll
      for (int j = 0; j < 4; j++) bf[j] = *(const f16x8*)&Bs[cur][(wn + j * 16 + fr) * 64 + swz];
      __builtin_amdgcn_s_setprio(1);
#pragma unroll
      for (int i = 0; i < 4; i++)
#pragma unroll
        for (int j = 0; j < 4; j++)
          acc[i][j] = __builtin_amdgcn_mfma_f32_16x16x32_f16(af[i], bf[j], acc[i][j], 0, 0, 0);
      __builtin_amdgcn_s_setprio(0);
    }
    asm volatile("s_waitcnt lgkmcnt(0)" ::: "memory");
    __builtin_amdgcn_s_barrier();
    const bool issue = (it + 2 < iters);
    if (issue) stage(cur, (it + 2) * 64);
    if (it + 1 < iters) {
      if (issue) asm volatile("s_waitcnt vmcnt(8)" ::: "memory");
      else       asm volatile("s_waitcnt vmcnt(0)" ::: "memory");
      __builtin_amdgcn_s_barrier();
    }
  }
  float* Pz = P + (((size_t)z * 32 + tile) * 4 + wave) * 4096;
#pragma unroll
  for (int i = 0; i < 4; i++)
#pragma unroll
    for (int j = 0; j < 4; j++)
#pragma unroll
      for (int rr = 0; rr < 4; rr++)
        Pz[((i * 4 + j) * 4 + rr) * 64 + lane] = acc[i][j][rr];
}

// ---- GEMM3 fused: reduce gemm2 partials (z-sum + b2 + relu) inside hs staging,
// then part3[z3][n][147] = h2_tile @ w3^T. Each h2 element is produced by exactly
// one (nb, z3) block -> reduce fusion is traffic-neutral, removes h2 round-trip.
__global__ __launch_bounds__(256) void gemm3_fused(const float* __restrict__ part2,
                                                   const float* __restrict__ b2,
                                                   const float* __restrict__ w3,
                                                   float* __restrict__ part3) {
  __shared__ float hs[8][128];
  const int n0 = blockIdx.x * 8;
  const int z3 = blockIdx.y;
  const int tid = threadIdx.x;
  const int MN = NROI * FC;
  {
    const int idx4 = tid * 4;            // 256 thr x 4 = 1024 elems
    const int nn = idx4 >> 7;
    const int kk = idx4 & 127;
    const int row = n0 + nn;
    const int col = z3 * 128 + kk;
    // invert gemm_lds (128x128) blocked-P layout
    const int bx = (row >> 7) & 3;
    const int by = (col >> 7) & 7;
    const int wv = ((row >> 6) & 1) | (((col >> 6) & 1) << 1);
    const int q  = ((row >> 4) & 3) * 16 + ((col >> 4) & 3) * 4 + (row & 3);
    const int l0 = ((row >> 2) & 3) * 16 + (col & 15);
    const int tile = by * 4 + bx;
    const size_t base = (size_t)((tile * 4 + wv) * 4096 + q * 64 + l0);
    float4 s = *(const float4*)(part2 + base);
#pragma unroll
    for (int z2 = 1; z2 < 8; z2++) {
      float4 t = *(const float4*)(part2 + (size_t)z2 * MN + base);
      s.x += t.x; s.y += t.y; s.z += t.z; s.w += t.w;
    }
    float4 bv = *(const float4*)(b2 + col);
    s.x = fmaxf(s.x + bv.x, 0.0f);
    s.y = fmaxf(s.y + bv.y, 0.0f);
    s.z = fmaxf(s.z + bv.z, 0.0f);
    s.w = fmaxf(s.w + bv.w, 0.0f);
    *(float4*)(&hs[nn][kk]) = s;
  }
  __syncthreads();
  const int j = tid;
  if (j < 147) {
    const float* wr = w3 + (size_t)j * FC + z3 * 128;
    float acc[8] = {0, 0, 0, 0, 0, 0, 0, 0};
    for (int k = 0; k < 128; k += 4) {
      float4 wv = *(const float4*)(wr + k);
#pragma unroll
      for (int nn = 0; nn < 8; nn++)
        acc[nn] += hs[nn][k] * wv.x + hs[nn][k + 1] * wv.y +
                   hs[nn][k + 2] * wv.z + hs[nn][k + 3] * wv.w;
    }
#pragma unroll
    for (int nn = 0; nn < 8; nn++)
      part3[((size_t)z3 * NROI + n0 + nn) * 147 + j] = acc[nn];
  }
}

extern "C" void kernel_launch(void* const* d_in, const int* in_sizes, int n_in,
                              void* d_out, int out_size, void* d_ws, size_t ws_size,
                              hipStream_t stream) {
  const float* feat = (const float*)d_in[0];
  const float* rois = (const float*)d_in[1];
  const float* w1 = (const float*)d_in[2];
  const float* b1 = (const float*)d_in[3];
  const float* w2 = (const float*)d_in[4];
  const float* b2 = (const float*)d_in[5];
  const float* w3 = (const float*)d_in[6];
  const float* b3 = (const float*)d_in[7];
  float* out = (float*)d_out;
  char* ws = (char*)d_ws;

  // workspace carve (~86.1 MB total)
  half_t* featT = (half_t*)ws;                        // 10,240,000 B
  half_t* xh    = (half_t*)(ws + 10240000);           // 12,845,056 B  (k = c*49+p)
  half_t* w1h   = (half_t*)(ws + 23085056);           // 25,690,112 B
  half_t* w2h   = (half_t*)(ws + 48775168);           //  2,097,152 B
  half_t* h1    = (half_t*)(ws + 50872320);           //  1,048,576 B
  float*  part  = (float*)(ws + 54319104);            // 29,360,128 B (gemm1 SK=14 / gemm2 SK=8)
  float*  part3 = (float*)(ws + 83679232);            //  2,408,448 B (gemm3 partials)

  const int MN = NROI * FC;  // 524288

  prep<<<dim3(18576), dim3(256), 0, stream>>>(feat, featT, w1, w1h, w2, w2h);
  pool_kernel<false><<<dim3(NROI), dim3(512), 0, stream>>>(featT, rois, nullptr, nullptr, xh, nullptr);

  // GEMM1: (512x12544) @ (1024x12544)^T -> 256x128 tiles, SK=14, 224 blocks, XCD-swizzled
  gemm_lds_w<14><<<dim3(2, 8, 14), dim3(512), 0, stream>>>(xh, w1h, part, KDIM);
  reduce_w<true, true, 14><<<dim3(MN / 1024), dim3(256), 0, stream>>>(part, b1, (void*)h1, MN, FC);

  // GEMM2: (512x1024) @ (1024x1024)^T -> SK=8, 256 blocks, XCD-swizzled
  gemm_lds<8><<<dim3(4, 8, 8), dim3(256), 0, stream>>>(h1, w2h, part, FC);

  // GEMM3 (+fused reduce2): part3 = relu(sum(part)+b2) @ w3^T; z-reduce+b3 folded into pool2
  gemm3_fused<<<dim3(64, 8), dim3(256), 0, stream>>>(part, b2, w3, part3);
  pool_kernel<true><<<dim3(NROI), dim3(512), 0, stream>>>(featT, rois, part3, b3, nullptr, out);
}

// Round 10
// 218.097 us; speedup vs baseline: 1.0169x; 1.0169x over previous
//
#include <hip/hip_runtime.h>

// Problem constants (fixed by setup_inputs)
#define BB 2
#define CC 256
#define HH 100
#define WW 100
#define NROI 512
#define KDIM 12544   // 49*256
#define FC 1024

typedef _Float16 half_t;
typedef _Float16 f16x2 __attribute__((ext_vector_type(2)));
typedef _Float16 f16x8 __attribute__((ext_vector_type(8)));
typedef _Float16 f16x4 __attribute__((ext_vector_type(4)));
typedef float f32x4 __attribute__((ext_vector_type(4)));

// async global->LDS DMA, 16B per lane, wave-uniform LDS base + lane*16
__device__ __forceinline__ void gload16(const half_t* g, half_t* l) {
  __builtin_amdgcn_global_load_lds(
      (const __attribute__((address_space(1))) unsigned int*)g,
      (__attribute__((address_space(3))) unsigned int*)l, 16, 0, 0);
}

// ---------------- fused prep: w1/w2 fp32->fp16 converts + feat transpose ----------------
__global__ __launch_bounds__(256) void prep(const float* __restrict__ feat,
                                            half_t* __restrict__ featT,
                                            const float* __restrict__ w1,
                                            half_t* __restrict__ w1h,
                                            const float* __restrict__ w2,
                                            half_t* __restrict__ w2h) {
  int bid = blockIdx.x;
  if (bid < 12544) {                       // w1: FC*KDIM = 12,845,056 elems
    int i4 = (bid * 256 + threadIdx.x) * 4;
    float4 v = *(const float4*)(w1 + i4);
    f16x4 o;
    o[0] = (half_t)v.x; o[1] = (half_t)v.y; o[2] = (half_t)v.z; o[3] = (half_t)v.w;
    *(f16x4*)(w1h + i4) = o;
    return;
  }
  bid -= 12544;
  if (bid < 1024) {                        // w2: FC*FC = 1,048,576 elems
    int i4 = (bid * 256 + threadIdx.x) * 4;
    float4 v = *(const float4*)(w2 + i4);
    f16x4 o;
    o[0] = (half_t)v.x; o[1] = (half_t)v.y; o[2] = (half_t)v.z; o[3] = (half_t)v.w;
    *(f16x4*)(w2h + i4) = o;
    return;
  }
  bid -= 1024;                             // transpose: 313*8*2 = 5008 blocks
  __shared__ float tile[32][33];
  const int bx = bid % 313;
  const int rem = bid / 313;
  const int by = rem & 7;
  const int bz = rem >> 3;
  const int tx = threadIdx.x & 31, ty = threadIdx.x >> 5;
  const int hw0 = bx * 32;
  const int c0 = by * 32;
  const float* fb = feat + (size_t)bz * CC * (HH * WW);
#pragma unroll
  for (int i = 0; i < 4; i++) {
    int c = c0 + ty + i * 8;
    int hw = hw0 + tx;
    tile[ty + i * 8][tx] = (hw < HH * WW) ? fb[(size_t)c * (HH * WW) + hw] : 0.0f;
  }
  __syncthreads();
  half_t* ob = featT + (size_t)bz * (HH * WW) * CC;
#pragma unroll
  for (int i = 0; i < 4; i++) {
    int hw = hw0 + ty + i * 8;
    int c = c0 + tx;
    if (hw < HH * WW) ob[(size_t)hw * CC + c] = (half_t)tile[tx][ty + i * 8];
  }
}

// ---------------- deformable PSROI pooling, one block (512 thr) per ROI ----------------
// PASS2: om = split-K partials part3[z][n][147]; z-reduce + b3 folded into phase 1.
// Phase 2: lane = (pixel-half, 8 channels); 8 pair-gathers (16 pixels) in flight.
struct PixW { int idx; float w; };

template <bool PASS2>
__global__ __launch_bounds__(512) void pool_kernel(const half_t* __restrict__ featT,
                                                   const float* __restrict__ rois,
                                                   const float* __restrict__ part3,
                                                   const float* __restrict__ b3,
                                                   half_t* __restrict__ xout,
                                                   float* __restrict__ out) {
  __shared__ __align__(16) PixW s_pix[49 * 32];       // <=25 pixels, pad to x16
  __shared__ int s_cnt[49];
  __shared__ float s_scale[49];
  __shared__ float  s_outf[PASS2 ? KDIM : 1];
  __shared__ half_t s_outh[PASS2 ? 1 : KDIM];

  const int n = blockIdx.x;
  const int tid = threadIdx.x;
  const float* r = rois + n * 5;
  const int b = (int)r[0];
  const float rsw = rintf(r[1]) * 0.0625f - 0.5f;
  const float rsh = rintf(r[2]) * 0.0625f - 0.5f;
  const float rew = (rintf(r[3]) + 1.0f) * 0.0625f - 0.5f;
  const float reh = (rintf(r[4]) + 1.0f) * 0.0625f - 0.5f;
  const float roi_w = fmaxf(rew - rsw, 0.1f);
  const float roi_h = fmaxf(reh - rsh, 0.1f);
  const float bin_h = roi_h / 7.0f, bin_w = roi_w / 7.0f;
  const float sub_h = bin_h * 0.25f, sub_w = bin_w * 0.25f;
  const half_t* fb = featT + (size_t)b * (HH * WW) * CC;

  if (tid < 49) {
    const int p = tid, ph = p / 7, pw = p - ph * 7;
    float tx = 0.0f, ty = 0.0f, mask = 1.0f;
    if (PASS2) {
      float o0 = b3[p], o1 = b3[49 + p], o2 = b3[98 + p];
#pragma unroll
      for (int zz = 0; zz < 8; zz++) {
        const float* pz = part3 + ((size_t)zz * NROI + n) * 147;
        o0 += pz[p]; o1 += pz[49 + p]; o2 += pz[98 + p];
      }
      tx = o0 * 0.1f;
      ty = o1 * 0.1f;
      mask = 1.0f / (1.0f + expf(-o2));
    }
    const float hst = (float)ph * bin_h + rsh + ty * roi_h;
    const float wst = (float)pw * bin_w + rsw + tx * roi_w;
    float wh[6] = {0, 0, 0, 0, 0, 0};
    float hc0 = fminf(fmaxf(hst, 0.0f), 99.0f);
    const int r0 = (int)hc0;
    int rtop = r0;
    float vsh = 0.0f;
#pragma unroll
    for (int i = 0; i < 4; i++) {
      float h = hst + (float)i * sub_h;
      bool v = (h >= -0.5f) && (h <= (float)HH - 0.5f);
      float hc = fminf(fmaxf(h, 0.0f), 99.0f);
      int h0 = (int)hc;
      float lh = hc - (float)h0;
      int h1 = min(h0 + 1, HH - 1);
      if (v) { wh[h0 - r0] += 1.0f - lh; wh[h1 - r0] += lh; vsh += 1.0f; }
      rtop = h1;
    }
    float wwc[6] = {0, 0, 0, 0, 0, 0};
    float wc0 = fminf(fmaxf(wst, 0.0f), 99.0f);
    const int c0 = (int)wc0;
    int ctop = c0;
    float vsw = 0.0f;
#pragma unroll
    for (int j = 0; j < 4; j++) {
      float w = wst + (float)j * sub_w;
      bool v = (w >= -0.5f) && (w <= (float)WW - 0.5f);
      float wc = fminf(fmaxf(w, 0.0f), 99.0f);
      int w0 = (int)wc;
      float lw = wc - (float)w0;
      int w1 = min(w0 + 1, WW - 1);
      if (v) { wwc[w0 - c0] += 1.0f - lw; wwc[w1 - c0] += lw; vsw += 1.0f; }
      ctop = w1;
    }
    const int nr = rtop - r0 + 1, nc = ctop - c0 + 1;
    float cntf = vsh * vsw;
    s_scale[p] = (cntf > 0.0f) ? mask / cntf : 0.0f;
    PixW* dst = &s_pix[p * 32];
    int m = 0;
    for (int ri = 0; ri < nr; ri++) {
      int rowoff = (r0 + ri) * WW + c0;
      for (int ci = 0; ci < nc; ci++) {
        dst[m].idx = (rowoff + ci) * CC;
        dst[m].w = wh[ri] * wwc[ci];
        m++;
      }
    }
    while (m & 15) { dst[m].idx = 0; dst[m].w = 0.0f; m++; }   // pad to mult of 16
    s_cnt[p] = m;
  }
  __syncthreads();

  // ---- phase 2: wave per bin; lane = (pixel-half, 8 channels); 8 pair-gathers in flight ----
  const int wv = tid >> 6;
  const int lane = tid & 63;
  const int half = lane >> 5;              // 0: even pixel, 1: odd pixel
  const int c8 = (lane & 31) * 8;          // 8 channels per lane, 32 lanes = 256 ch
  for (int p = wv; p < 49; p += 8) {
    const int cnt = s_cnt[p];              // wave-uniform LDS read
    const PixW* cp = &s_pix[p * 32];
    float a0 = 0, a1 = 0, a2 = 0, a3 = 0, a4 = 0, a5 = 0, a6 = 0, a7 = 0;
    for (int q = 0; q < cnt; q += 16) {
      PixW e0 = cp[q + 0 + half];          // 2-way broadcast (free)
      PixW e1 = cp[q + 2 + half];
      PixW e2 = cp[q + 4 + half];
      PixW e3 = cp[q + 6 + half];
      PixW e4 = cp[q + 8 + half];
      PixW e5 = cp[q + 10 + half];
      PixW e6 = cp[q + 12 + half];
      PixW e7 = cp[q + 14 + half];
      f16x8 v0 = *(const f16x8*)(fb + e0.idx + c8);
      f16x8 v1 = *(const f16x8*)(fb + e1.idx + c8);
      f16x8 v2 = *(const f16x8*)(fb + e2.idx + c8);
      f16x8 v3 = *(const f16x8*)(fb + e3.idx + c8);
      f16x8 v4 = *(const f16x8*)(fb + e4.idx + c8);
      f16x8 v5 = *(const f16x8*)(fb + e5.idx + c8);
      f16x8 v6 = *(const f16x8*)(fb + e6.idx + c8);
      f16x8 v7 = *(const f16x8*)(fb + e7.idx + c8);
      a0 += e0.w * (float)v0[0] + e1.w * (float)v1[0] + e2.w * (float)v2[0] + e3.w * (float)v3[0]
          + e4.w * (float)v4[0] + e5.w * (float)v5[0] + e6.w * (float)v6[0] + e7.w * (float)v7[0];
      a1 += e0.w * (float)v0[1] + e1.w * (float)v1[1] + e2.w * (float)v2[1] + e3.w * (float)v3[1]
          + e4.w * (float)v4[1] + e5.w * (float)v5[1] + e6.w * (float)v6[1] + e7.w * (float)v7[1];
      a2 += e0.w * (float)v0[2] + e1.w * (float)v1[2] + e2.w * (float)v2[2] + e3.w * (float)v3[2]
          + e4.w * (float)v4[2] + e5.w * (float)v5[2] + e6.w * (float)v6[2] + e7.w * (float)v7[2];
      a3 += e0.w * (float)v0[3] + e1.w * (float)v1[3] + e2.w * (float)v2[3] + e3.w * (float)v3[3]
          + e4.w * (float)v4[3] + e5.w * (float)v5[3] + e6.w * (float)v6[3] + e7.w * (float)v7[3];
      a4 += e0.w * (float)v0[4] + e1.w * (float)v1[4] + e2.w * (float)v2[4] + e3.w * (float)v3[4]
          + e4.w * (float)v4[4] + e5.w * (float)v5[4] + e6.w * (float)v6[4] + e7.w * (float)v7[4];
      a5 += e0.w * (float)v0[5] + e1.w * (float)v1[5] + e2.w * (float)v2[5] + e3.w * (float)v3[5]
          + e4.w * (float)v4[5] + e5.w * (float)v5[5] + e6.w * (float)v6[5] + e7.w * (float)v7[5];
      a6 += e0.w * (float)v0[6] + e1.w * (float)v1[6] + e2.w * (float)v2[6] + e3.w * (float)v3[6]
          + e4.w * (float)v4[6] + e5.w * (float)v5[6] + e6.w * (float)v6[6] + e7.w * (float)v7[6];
      a7 += e0.w * (float)v0[7] + e1.w * (float)v1[7] + e2.w * (float)v2[7] + e3.w * (float)v3[7]
          + e4.w * (float)v4[7] + e5.w * (float)v5[7] + e6.w * (float)v6[7] + e7.w * (float)v7[7];
    }
    // combine even/odd pixel halves (lanes l and l+32 hold same channels)
    a0 += __shfl_xor(a0, 32); a1 += __shfl_xor(a1, 32);
    a2 += __shfl_xor(a2, 32); a3 += __shfl_xor(a3, 32);
    a4 += __shfl_xor(a4, 32); a5 += __shfl_xor(a5, 32);
    a6 += __shfl_xor(a6, 32); a7 += __shfl_xor(a7, 32);
    if (half == 0) {
      float sc = s_scale[p];
      a0 *= sc; a1 *= sc; a2 *= sc; a3 *= sc; a4 *= sc; a5 *= sc; a6 *= sc; a7 *= sc;
      if (PASS2) {
        s_outf[(c8 + 0) * 49 + p] = a0;
        s_outf[(c8 + 1) * 49 + p] = a1;
        s_outf[(c8 + 2) * 49 + p] = a2;
        s_outf[(c8 + 3) * 49 + p] = a3;
        s_outf[(c8 + 4) * 49 + p] = a4;
        s_outf[(c8 + 5) * 49 + p] = a5;
        s_outf[(c8 + 6) * 49 + p] = a6;
        s_outf[(c8 + 7) * 49 + p] = a7;
      } else {
        s_outh[(c8 + 0) * 49 + p] = (half_t)a0;
        s_outh[(c8 + 1) * 49 + p] = (half_t)a1;
        s_outh[(c8 + 2) * 49 + p] = (half_t)a2;
        s_outh[(c8 + 3) * 49 + p] = (half_t)a3;
        s_outh[(c8 + 4) * 49 + p] = (half_t)a4;
        s_outh[(c8 + 5) * 49 + p] = (half_t)a5;
        s_outh[(c8 + 6) * 49 + p] = (half_t)a6;
        s_outh[(c8 + 7) * 49 + p] = (half_t)a7;
      }
    }
  }
  __syncthreads();

  if (PASS2) {
    float* ob = out + (size_t)n * KDIM;
    for (int l = tid * 4; l < KDIM; l += 2048)
      *(float4*)(ob + l) = *(const float4*)(s_outf + l);
  } else {
    half_t* ob = xout + (size_t)n * KDIM;
    for (int l = tid * 8; l < KDIM; l += 4096)
      *(f16x8*)(ob + l) = *(const f16x8*)(s_outh + l);
  }
}

// ---- split-K fp16 MFMA GEMM (GEMM1+GEMM2), 128x128 tile, 256 thr / 4 waves ----
// T3/T4: global_load_lds + counted vmcnt(8), double-buffered LDS (64 KB -> 2
// blocks/CU; co-residency hides each block's barrier drains -- measured better
// than the 256x128/1-block variant). Source-side bank swizzle; XCD z-grouping.
// P layout: [z][tile=by*4+bx][wave 0..3][q=(i*4+j)*4+rr][lane]
template <int SK>
__global__ __launch_bounds__(256, 2) void gemm_lds(const half_t* __restrict__ A,
                                                   const half_t* __restrict__ B,
                                                   float* __restrict__ P, int K) {
  __shared__ half_t As[2][128 * 64];   // 32 KB
  __shared__ half_t Bs[2][128 * 64];   // 32 KB
  const int d = blockIdx.x + gridDim.x * (blockIdx.y + gridDim.y * blockIdx.z);
  const int g = (d & 7) * (SK * 4) + (d >> 3);   // bijective: 32*SK blocks, %8==0
  const int z = g >> 5;
  const int tile = g & 31;
  const int m0 = (tile & 3) * 128;
  const int n0 = (tile >> 2) * 128;
  const int Kc = K / SK;
  const int kbeg = z * Kc;
  const int tid = threadIdx.x;
  const int lane = tid & 63;
  const int wave = tid >> 6;
  const int wm = (wave & 1) * 64;
  const int wn = (wave >> 1) * 64;
  const int fr = lane & 15;
  const int kc0 = lane >> 4;
  const int lr = lane >> 3;
  const int lc = (lane & 7) ^ lr;         // pre-swizzled global 16B-chunk
  const half_t* Ag = A + (size_t)(m0 + wave * 8 + lr) * K + kbeg + lc * 8;
  const half_t* Bg = B + (size_t)(n0 + wave * 8 + lr) * K + kbeg + lc * 8;
  f32x4 acc[4][4] = {};

  auto stage = [&](int buf, int ko) {
#pragma unroll
    for (int s = 0; s < 4; s++)
      gload16(Ag + (size_t)(32 * s) * K + ko, &As[buf][s * 2048 + wave * 512]);
#pragma unroll
    for (int s = 0; s < 4; s++)
      gload16(Bg + (size_t)(32 * s) * K + ko, &Bs[buf][s * 2048 + wave * 512]);
  };

  const int iters = Kc >> 6;
  stage(0, 0);
  if (iters > 1) {
    stage(1, 64);
    asm volatile("s_waitcnt vmcnt(8)" ::: "memory");   // buf0 complete, buf1 in flight
  } else {
    asm volatile("s_waitcnt vmcnt(0)" ::: "memory");
  }
  __builtin_amdgcn_s_barrier();

  for (int it = 0; it < iters; it++) {
    const int cur = it & 1;
#pragma unroll
    for (int ks = 0; ks < 2; ks++) {
      const int swz = ((kc0 + ks * 4) ^ (fr & 7)) * 8;
      f16x8 af[4], bf[4];
#pragma unroll
      for (int i = 0; i < 4; i++) af[i] = *(const f16x8*)&As[cur][(wm + i * 16 + fr) * 64 + swz];
#pragma unroll
      for (int j = 0; j < 4; j++) bf[j] = *(const f16x8*)&Bs[cur][(wn + j * 16 + fr) * 64 + swz];
      __builtin_amdgcn_s_setprio(1);
#pragma unroll
      for (int i = 0; i < 4; i++)
#pragma unroll
        for (int j = 0; j < 4; j++)
          acc[i][j] = __builtin_amdgcn_mfma_f32_16x16x32_f16(af[i], bf[j], acc[i][j], 0, 0, 0);
      __builtin_amdgcn_s_setprio(0);
    }
    asm volatile("s_waitcnt lgkmcnt(0)" ::: "memory");
    __builtin_amdgcn_s_barrier();
    const bool issue = (it + 2 < iters);
    if (issue) stage(cur, (it + 2) * 64);
    if (it + 1 < iters) {
      if (issue) asm volatile("s_waitcnt vmcnt(8)" ::: "memory");
      else       asm volatile("s_waitcnt vmcnt(0)" ::: "memory");
      __builtin_amdgcn_s_barrier();
    }
  }
  float* Pz = P + (((size_t)z * 32 + tile) * 4 + wave) * 4096;
#pragma unroll
  for (int i = 0; i < 4; i++)
#pragma unroll
    for (int j = 0; j < 4; j++)
#pragma unroll
      for (int rr = 0; rr < 4; rr++)
        Pz[((i * 4 + j) * 4 + rr) * 64 + lane] = acc[i][j][rr];
}

// ---- reduce SK blocked partials + bias (+relu), write fp16 or fp32 (128x128 layout) ----
template <bool OUT16, bool RELU, int SK>
__global__ __launch_bounds__(256) void reduce_blocked(const float* __restrict__ P,
                                                      const float* __restrict__ bias,
                                                      void* __restrict__ out,
                                                      int MN, int N) {
  int i4 = (blockIdx.x * 256 + threadIdx.x) * 4;
  if (i4 >= MN) return;
  float4 s = *(const float4*)(P + i4);
#pragma unroll
  for (int z = 1; z < SK; z++) {
    float4 t = *(const float4*)(P + (size_t)z * MN + i4);
    s.x += t.x; s.y += t.y; s.z += t.z; s.w += t.w;
  }
  const int lane0 = i4 & 63;
  const int q     = (i4 >> 6) & 63;
  const int wave  = (i4 >> 12) & 3;
  const int bx    = (i4 >> 14) & 3;
  const int by    = (i4 >> 16) & 7;
  const int rr = q & 3, j_ = (q >> 2) & 3, i_ = q >> 4;
  const int row = bx * 128 + (wave & 1) * 64 + i_ * 16 + (lane0 >> 4) * 4 + rr;
  const int col = by * 128 + (wave >> 1) * 64 + j_ * 16 + (lane0 & 15);
  float4 bv = *(const float4*)(bias + col);
  s.x += bv.x; s.y += bv.y; s.z += bv.z; s.w += bv.w;
  if (RELU) {
    s.x = fmaxf(s.x, 0.0f); s.y = fmaxf(s.y, 0.0f);
    s.z = fmaxf(s.z, 0.0f); s.w = fmaxf(s.w, 0.0f);
  }
  size_t o = (size_t)row * N + col;
  if (OUT16) {
    f16x4 ov;
    ov[0] = (half_t)s.x; ov[1] = (half_t)s.y; ov[2] = (half_t)s.z; ov[3] = (half_t)s.w;
    *(f16x4*)((half_t*)out + o) = ov;
  } else {
    *(float4*)((float*)out + o) = s;
  }
}

// ---- GEMM3 fused: reduce gemm2 partials (z-sum + b2 + relu) inside hs staging,
// then part3[z3][n][147] = h2_tile @ w3^T. Each h2 element is produced by exactly
// one (nb, z3) block -> reduce fusion is traffic-neutral, removes h2 round-trip.
__global__ __launch_bounds__(256) void gemm3_fused(const float* __restrict__ part2,
                                                   const float* __restrict__ b2,
                                                   const float* __restrict__ w3,
                                                   float* __restrict__ part3) {
  __shared__ float hs[8][128];
  const int n0 = blockIdx.x * 8;
  const int z3 = blockIdx.y;
  const int tid = threadIdx.x;
  const int MN = NROI * FC;
  {
    const int idx4 = tid * 4;            // 256 thr x 4 = 1024 elems
    const int nn = idx4 >> 7;
    const int kk = idx4 & 127;
    const int row = n0 + nn;
    const int col = z3 * 128 + kk;
    // invert gemm_lds (128x128) blocked-P layout
    const int bx = (row >> 7) & 3;
    const int by = (col >> 7) & 7;
    const int wv = ((row >> 6) & 1) | (((col >> 6) & 1) << 1);
    const int q  = ((row >> 4) & 3) * 16 + ((col >> 4) & 3) * 4 + (row & 3);
    const int l0 = ((row >> 2) & 3) * 16 + (col & 15);
    const int tile = by * 4 + bx;
    const size_t base = (size_t)((tile * 4 + wv) * 4096 + q * 64 + l0);
    float4 s = *(const float4*)(part2 + base);
#pragma unroll
    for (int z2 = 1; z2 < 8; z2++) {
      float4 t = *(const float4*)(part2 + (size_t)z2 * MN + base);
      s.x += t.x; s.y += t.y; s.z += t.z; s.w += t.w;
    }
    float4 bv = *(const float4*)(b2 + col);
    s.x = fmaxf(s.x + bv.x, 0.0f);
    s.y = fmaxf(s.y + bv.y, 0.0f);
    s.z = fmaxf(s.z + bv.z, 0.0f);
    s.w = fmaxf(s.w + bv.w, 0.0f);
    *(float4*)(&hs[nn][kk]) = s;
  }
  __syncthreads();
  const int j = tid;
  if (j < 147) {
    const float* wr = w3 + (size_t)j * FC + z3 * 128;
    float acc[8] = {0, 0, 0, 0, 0, 0, 0, 0};
    for (int k = 0; k < 128; k += 4) {
      float4 wv = *(const float4*)(wr + k);
#pragma unroll
      for (int nn = 0; nn < 8; nn++)
        acc[nn] += hs[nn][k] * wv.x + hs[nn][k + 1] * wv.y +
                   hs[nn][k + 2] * wv.z + hs[nn][k + 3] * wv.w;
    }
#pragma unroll
    for (int nn = 0; nn < 8; nn++)
      part3[((size_t)z3 * NROI + n0 + nn) * 147 + j] = acc[nn];
  }
}

extern "C" void kernel_launch(void* const* d_in, const int* in_sizes, int n_in,
                              void* d_out, int out_size, void* d_ws, size_t ws_size,
                              hipStream_t stream) {
  const float* feat = (const float*)d_in[0];
  const float* rois = (const float*)d_in[1];
  const float* w1 = (const float*)d_in[2];
  const float* b1 = (const float*)d_in[3];
  const float* w2 = (const float*)d_in[4];
  const float* b2 = (const float*)d_in[5];
  const float* w3 = (const float*)d_in[6];
  const float* b3 = (const float*)d_in[7];
  float* out = (float*)d_out;
  char* ws = (char*)d_ws;

  // workspace carve (~86.1 MB total)
  half_t* featT = (half_t*)ws;                        // 10,240,000 B
  half_t* xh    = (half_t*)(ws + 10240000);           // 12,845,056 B  (k = c*49+p)
  half_t* w1h   = (half_t*)(ws + 23085056);           // 25,690,112 B
  half_t* w2h   = (half_t*)(ws + 48775168);           //  2,097,152 B
  half_t* h1    = (half_t*)(ws + 50872320);           //  1,048,576 B
  float*  part  = (float*)(ws + 54319104);            // 29,360,128 B (gemm1 SK=14 / gemm2 SK=8)
  float*  part3 = (float*)(ws + 83679232);            //  2,408,448 B (gemm3 partials)

  const int MN = NROI * FC;  // 524288

  prep<<<dim3(18576), dim3(256), 0, stream>>>(feat, featT, w1, w1h, w2, w2h);
  pool_kernel<false><<<dim3(NROI), dim3(512), 0, stream>>>(featT, rois, nullptr, nullptr, xh, nullptr);

  // GEMM1: (512x12544) @ (1024x12544)^T -> 128x128 tiles, SK=14, 448 blocks, XCD-swizzled
  gemm_lds<14><<<dim3(4, 8, 14), dim3(256), 0, stream>>>(xh, w1h, part, KDIM);
  reduce_blocked<true, true, 14><<<dim3(MN / 1024), dim3(256), 0, stream>>>(part, b1, (void*)h1, MN, FC);

  // GEMM2: (512x1024) @ (1024x1024)^T -> SK=8, 256 blocks, XCD-swizzled
  gemm_lds<8><<<dim3(4, 8, 8), dim3(256), 0, stream>>>(h1, w2h, part, FC);

  // GEMM3 (+fused reduce2): part3 = relu(sum(part)+b2) @ w3^T; z-reduce+b3 folded into pool2
  gemm3_fused<<<dim3(64, 8), dim3(256), 0, stream>>>(part, b2, w3, part3);
  pool_kernel<true><<<dim3(NROI), dim3(512), 0, stream>>>(featT, rois, part3, b3, nullptr, out);
}

// Round 11
// 215.788 us; speedup vs baseline: 1.0278x; 1.0107x over previous
//
#include <hip/hip_runtime.h>

// Problem constants (fixed by setup_inputs)
#define BB 2
#define CC 256
#define HH 100
#define WW 100
#define NROI 512
#define KDIM 12544   // 49*256
#define FC 1024

typedef _Float16 half_t;
typedef _Float16 f16x2 __attribute__((ext_vector_type(2)));
typedef _Float16 f16x8 __attribute__((ext_vector_type(8)));
typedef _Float16 f16x4 __attribute__((ext_vector_type(4)));
typedef float f32x4 __attribute__((ext_vector_type(4)));

// async global->LDS DMA, 16B per lane, wave-uniform LDS base + lane*16
__device__ __forceinline__ void gload16(const half_t* g, half_t* l) {
  __builtin_amdgcn_global_load_lds(
      (const __attribute__((address_space(1))) unsigned int*)g,
      (__attribute__((address_space(3))) unsigned int*)l, 16, 0, 0);
}

// ---------------- prep0: feat transpose + w2 convert ----------------
// blocks [0,5008): transpose; [5008,6032): w2 convert. w1 convert moved into the
// pool1 launch (overlaps the latency-bound gather phase with BW-bound streaming).
__global__ __launch_bounds__(256) void prep0(const float* __restrict__ feat,
                                             half_t* __restrict__ featT,
                                             const float* __restrict__ w2,
                                             half_t* __restrict__ w2h) {
  int bid = blockIdx.x;
  if (bid >= 5008) {                       // w2: FC*FC = 1,048,576 elems
    int i4 = ((bid - 5008) * 256 + threadIdx.x) * 4;
    float4 v = *(const float4*)(w2 + i4);
    f16x4 o;
    o[0] = (half_t)v.x; o[1] = (half_t)v.y; o[2] = (half_t)v.z; o[3] = (half_t)v.w;
    *(f16x4*)(w2h + i4) = o;
    return;
  }
  __shared__ float tile[32][33];
  const int bx = bid % 313;
  const int rem = bid / 313;
  const int by = rem & 7;
  const int bz = rem >> 3;
  const int tx = threadIdx.x & 31, ty = threadIdx.x >> 5;
  const int hw0 = bx * 32;
  const int c0 = by * 32;
  const float* fb = feat + (size_t)bz * CC * (HH * WW);
#pragma unroll
  for (int i = 0; i < 4; i++) {
    int c = c0 + ty + i * 8;
    int hw = hw0 + tx;
    tile[ty + i * 8][tx] = (hw < HH * WW) ? fb[(size_t)c * (HH * WW) + hw] : 0.0f;
  }
  __syncthreads();
  half_t* ob = featT + (size_t)bz * (HH * WW) * CC;
#pragma unroll
  for (int i = 0; i < 4; i++) {
    int hw = hw0 + ty + i * 8;
    int c = c0 + tx;
    if (hw < HH * WW) ob[(size_t)hw * CC + c] = (half_t)tile[tx][ty + i * 8];
  }
}

// ---------------- deformable PSROI pooling, one block (512 thr) per ROI ----------------
// PASS1 fused with w1 fp32->fp16 convert: blocks [NROI, NROI+6272) stream-convert
// w1 while ROI blocks run the latency-bound gather -> overlap in one launch.
// PASS2: om = split-K partials part3[z][n][147]; z-reduce + b3 folded into phase 1.
// Phase 2: lane = (pixel-half, 8 channels); 8 pair-gathers (16 pixels) in flight.
struct PixW { int idx; float w; };

template <bool PASS2>
__global__ __launch_bounds__(512) void pool_kernel(const half_t* __restrict__ featT,
                                                   const float* __restrict__ rois,
                                                   const float* __restrict__ part3,
                                                   const float* __restrict__ b3,
                                                   half_t* __restrict__ xout,
                                                   float* __restrict__ out,
                                                   const float* __restrict__ w1,
                                                   half_t* __restrict__ w1h) {
  __shared__ __align__(16) PixW s_pix[49 * 32];       // <=25 pixels, pad to x16
  __shared__ int s_cnt[49];
  __shared__ float s_scale[49];
  __shared__ float  s_outf[PASS2 ? KDIM : 1];
  __shared__ half_t s_outh[PASS2 ? 1 : KDIM];

  const int n = blockIdx.x;
  const int tid = threadIdx.x;
  if (!PASS2 && n >= NROI) {               // w1 convert: 6272 blocks x 2048 elems
    int i4 = ((n - NROI) * 512 + tid) * 4;
    float4 v = *(const float4*)(w1 + i4);
    f16x4 o;
    o[0] = (half_t)v.x; o[1] = (half_t)v.y; o[2] = (half_t)v.z; o[3] = (half_t)v.w;
    *(f16x4*)(w1h + i4) = o;
    return;
  }
  const float* r = rois + n * 5;
  const int b = (int)r[0];
  const float rsw = rintf(r[1]) * 0.0625f - 0.5f;
  const float rsh = rintf(r[2]) * 0.0625f - 0.5f;
  const float rew = (rintf(r[3]) + 1.0f) * 0.0625f - 0.5f;
  const float reh = (rintf(r[4]) + 1.0f) * 0.0625f - 0.5f;
  const float roi_w = fmaxf(rew - rsw, 0.1f);
  const float roi_h = fmaxf(reh - rsh, 0.1f);
  const float bin_h = roi_h / 7.0f, bin_w = roi_w / 7.0f;
  const float sub_h = bin_h * 0.25f, sub_w = bin_w * 0.25f;
  const half_t* fb = featT + (size_t)b * (HH * WW) * CC;

  if (tid < 49) {
    const int p = tid, ph = p / 7, pw = p - ph * 7;
    float tx = 0.0f, ty = 0.0f, mask = 1.0f;
    if (PASS2) {
      float o0 = b3[p], o1 = b3[49 + p], o2 = b3[98 + p];
#pragma unroll
      for (int zz = 0; zz < 8; zz++) {
        const float* pz = part3 + ((size_t)zz * NROI + n) * 147;
        o0 += pz[p]; o1 += pz[49 + p]; o2 += pz[98 + p];
      }
      tx = o0 * 0.1f;
      ty = o1 * 0.1f;
      mask = 1.0f / (1.0f + expf(-o2));
    }
    const float hst = (float)ph * bin_h + rsh + ty * roi_h;
    const float wst = (float)pw * bin_w + rsw + tx * roi_w;
    float wh[6] = {0, 0, 0, 0, 0, 0};
    float hc0 = fminf(fmaxf(hst, 0.0f), 99.0f);
    const int r0 = (int)hc0;
    int rtop = r0;
    float vsh = 0.0f;
#pragma unroll
    for (int i = 0; i < 4; i++) {
      float h = hst + (float)i * sub_h;
      bool v = (h >= -0.5f) && (h <= (float)HH - 0.5f);
      float hc = fminf(fmaxf(h, 0.0f), 99.0f);
      int h0 = (int)hc;
      float lh = hc - (float)h0;
      int h1 = min(h0 + 1, HH - 1);
      if (v) { wh[h0 - r0] += 1.0f - lh; wh[h1 - r0] += lh; vsh += 1.0f; }
      rtop = h1;
    }
    float wwc[6] = {0, 0, 0, 0, 0, 0};
    float wc0 = fminf(fmaxf(wst, 0.0f), 99.0f);
    const int c0 = (int)wc0;
    int ctop = c0;
    float vsw = 0.0f;
#pragma unroll
    for (int j = 0; j < 4; j++) {
      float w = wst + (float)j * sub_w;
      bool v = (w >= -0.5f) && (w <= (float)WW - 0.5f);
      float wc = fminf(fmaxf(w, 0.0f), 99.0f);
      int w0 = (int)wc;
      float lw = wc - (float)w0;
      int w1_ = min(w0 + 1, WW - 1);
      if (v) { wwc[w0 - c0] += 1.0f - lw; wwc[w1_ - c0] += lw; vsw += 1.0f; }
      ctop = w1_;
    }
    const int nr = rtop - r0 + 1, nc = ctop - c0 + 1;
    float cntf = vsh * vsw;
    s_scale[p] = (cntf > 0.0f) ? mask / cntf : 0.0f;
    PixW* dst = &s_pix[p * 32];
    int m = 0;
    for (int ri = 0; ri < nr; ri++) {
      int rowoff = (r0 + ri) * WW + c0;
      for (int ci = 0; ci < nc; ci++) {
        dst[m].idx = (rowoff + ci) * CC;
        dst[m].w = wh[ri] * wwc[ci];
        m++;
      }
    }
    while (m & 15) { dst[m].idx = 0; dst[m].w = 0.0f; m++; }   // pad to mult of 16
    s_cnt[p] = m;
  }
  __syncthreads();

  // ---- phase 2: wave per bin; lane = (pixel-half, 8 channels); 8 pair-gathers in flight ----
  const int wv = tid >> 6;
  const int lane = tid & 63;
  const int half = lane >> 5;              // 0: even pixel, 1: odd pixel
  const int c8 = (lane & 31) * 8;          // 8 channels per lane, 32 lanes = 256 ch
  for (int p = wv; p < 49; p += 8) {
    const int cnt = s_cnt[p];              // wave-uniform LDS read
    const PixW* cp = &s_pix[p * 32];
    float a0 = 0, a1 = 0, a2 = 0, a3 = 0, a4 = 0, a5 = 0, a6 = 0, a7 = 0;
    for (int q = 0; q < cnt; q += 16) {
      PixW e0 = cp[q + 0 + half];          // 2-way broadcast (free)
      PixW e1 = cp[q + 2 + half];
      PixW e2 = cp[q + 4 + half];
      PixW e3 = cp[q + 6 + half];
      PixW e4 = cp[q + 8 + half];
      PixW e5 = cp[q + 10 + half];
      PixW e6 = cp[q + 12 + half];
      PixW e7 = cp[q + 14 + half];
      f16x8 v0 = *(const f16x8*)(fb + e0.idx + c8);
      f16x8 v1 = *(const f16x8*)(fb + e1.idx + c8);
      f16x8 v2 = *(const f16x8*)(fb + e2.idx + c8);
      f16x8 v3 = *(const f16x8*)(fb + e3.idx + c8);
      f16x8 v4 = *(const f16x8*)(fb + e4.idx + c8);
      f16x8 v5 = *(const f16x8*)(fb + e5.idx + c8);
      f16x8 v6 = *(const f16x8*)(fb + e6.idx + c8);
      f16x8 v7 = *(const f16x8*)(fb + e7.idx + c8);
      a0 += e0.w * (float)v0[0] + e1.w * (float)v1[0] + e2.w * (float)v2[0] + e3.w * (float)v3[0]
          + e4.w * (float)v4[0] + e5.w * (float)v5[0] + e6.w * (float)v6[0] + e7.w * (float)v7[0];
      a1 += e0.w * (float)v0[1] + e1.w * (float)v1[1] + e2.w * (float)v2[1] + e3.w * (float)v3[1]
          + e4.w * (float)v4[1] + e5.w * (float)v5[1] + e6.w * (float)v6[1] + e7.w * (float)v7[1];
      a2 += e0.w * (float)v0[2] + e1.w * (float)v1[2] + e2.w * (float)v2[2] + e3.w * (float)v3[2]
          + e4.w * (float)v4[2] + e5.w * (float)v5[2] + e6.w * (float)v6[2] + e7.w * (float)v7[2];
      a3 += e0.w * (float)v0[3] + e1.w * (float)v1[3] + e2.w * (float)v2[3] + e3.w * (float)v3[3]
          + e4.w * (float)v4[3] + e5.w * (float)v5[3] + e6.w * (float)v6[3] + e7.w * (float)v7[3];
      a4 += e0.w * (float)v0[4] + e1.w * (float)v1[4] + e2.w * (float)v2[4] + e3.w * (float)v3[4]
          + e4.w * (float)v4[4] + e5.w * (float)v5[4] + e6.w * (float)v6[4] + e7.w * (float)v7[4];
      a5 += e0.w * (float)v0[5] + e1.w * (float)v1[5] + e2.w * (float)v2[5] + e3.w * (float)v3[5]
          + e4.w * (float)v4[5] + e5.w * (float)v5[5] + e6.w * (float)v6[5] + e7.w * (float)v7[5];
      a6 += e0.w * (float)v0[6] + e1.w * (float)v1[6] + e2.w * (float)v2[6] + e3.w * (float)v3[6]
          + e4.w * (float)v4[6] + e5.w * (float)v5[6] + e6.w * (float)v6[6] + e7.w * (float)v7[6];
      a7 += e0.w * (float)v0[7] + e1.w * (float)v1[7] + e2.w * (float)v2[7] + e3.w * (float)v3[7]
          + e4.w * (float)v4[7] + e5.w * (float)v5[7] + e6.w * (float)v6[7] + e7.w * (float)v7[7];
    }
    // combine even/odd pixel halves (lanes l and l+32 hold same channels)
    a0 += __shfl_xor(a0, 32); a1 += __shfl_xor(a1, 32);
    a2 += __shfl_xor(a2, 32); a3 += __shfl_xor(a3, 32);
    a4 += __shfl_xor(a4, 32); a5 += __shfl_xor(a5, 32);
    a6 += __shfl_xor(a6, 32); a7 += __shfl_xor(a7, 32);
    if (half == 0) {
      float sc = s_scale[p];
      a0 *= sc; a1 *= sc; a2 *= sc; a3 *= sc; a4 *= sc; a5 *= sc; a6 *= sc; a7 *= sc;
      if (PASS2) {
        s_outf[(c8 + 0) * 49 + p] = a0;
        s_outf[(c8 + 1) * 49 + p] = a1;
        s_outf[(c8 + 2) * 49 + p] = a2;
        s_outf[(c8 + 3) * 49 + p] = a3;
        s_outf[(c8 + 4) * 49 + p] = a4;
        s_outf[(c8 + 5) * 49 + p] = a5;
        s_outf[(c8 + 6) * 49 + p] = a6;
        s_outf[(c8 + 7) * 49 + p] = a7;
      } else {
        s_outh[(c8 + 0) * 49 + p] = (half_t)a0;
        s_outh[(c8 + 1) * 49 + p] = (half_t)a1;
        s_outh[(c8 + 2) * 49 + p] = (half_t)a2;
        s_outh[(c8 + 3) * 49 + p] = (half_t)a3;
        s_outh[(c8 + 4) * 49 + p] = (half_t)a4;
        s_outh[(c8 + 5) * 49 + p] = (half_t)a5;
        s_outh[(c8 + 6) * 49 + p] = (half_t)a6;
        s_outh[(c8 + 7) * 49 + p] = (half_t)a7;
      }
    }
  }
  __syncthreads();

  if (PASS2) {
    float* ob = out + (size_t)n * KDIM;
    for (int l = tid * 4; l < KDIM; l += 2048)
      *(float4*)(ob + l) = *(const float4*)(s_outf + l);
  } else {
    half_t* ob = xout + (size_t)n * KDIM;
    for (int l = tid * 8; l < KDIM; l += 4096)
      *(f16x8*)(ob + l) = *(const f16x8*)(s_outh + l);
  }
}

// ---- split-K fp16 MFMA GEMM (GEMM1+GEMM2), 128x128 tile, 256 thr / 4 waves ----
// T3/T4: global_load_lds + counted vmcnt(8), double-buffered LDS (64 KB -> 2
// blocks/CU; co-residency hides each block's barrier drains -- measured better
// than the 256x128/1-block variant). Source-side bank swizzle; XCD z-grouping.
// P layout: [z][tile=by*4+bx][wave 0..3][q=(i*4+j)*4+rr][lane]
template <int SK>
__global__ __launch_bounds__(256, 2) void gemm_lds(const half_t* __restrict__ A,
                                                   const half_t* __restrict__ B,
                                                   float* __restrict__ P, int K) {
  __shared__ half_t As[2][128 * 64];   // 32 KB
  __shared__ half_t Bs[2][128 * 64];   // 32 KB
  const int d = blockIdx.x + gridDim.x * (blockIdx.y + gridDim.y * blockIdx.z);
  const int g = (d & 7) * (SK * 4) + (d >> 3);   // bijective: 32*SK blocks, %8==0
  const int z = g >> 5;
  const int tile = g & 31;
  const int m0 = (tile & 3) * 128;
  const int n0 = (tile >> 2) * 128;
  const int Kc = K / SK;
  const int kbeg = z * Kc;
  const int tid = threadIdx.x;
  const int lane = tid & 63;
  const int wave = tid >> 6;
  const int wm = (wave & 1) * 64;
  const int wn = (wave >> 1) * 64;
  const int fr = lane & 15;
  const int kc0 = lane >> 4;
  const int lr = lane >> 3;
  const int lc = (lane & 7) ^ lr;         // pre-swizzled global 16B-chunk
  const half_t* Ag = A + (size_t)(m0 + wave * 8 + lr) * K + kbeg + lc * 8;
  const half_t* Bg = B + (size_t)(n0 + wave * 8 + lr) * K + kbeg + lc * 8;
  f32x4 acc[4][4] = {};

  auto stage = [&](int buf, int ko) {
#pragma unroll
    for (int s = 0; s < 4; s++)
      gload16(Ag + (size_t)(32 * s) * K + ko, &As[buf][s * 2048 + wave * 512]);
#pragma unroll
    for (int s = 0; s < 4; s++)
      gload16(Bg + (size_t)(32 * s) * K + ko, &Bs[buf][s * 2048 + wave * 512]);
  };

  const int iters = Kc >> 6;
  stage(0, 0);
  if (iters > 1) {
    stage(1, 64);
    asm volatile("s_waitcnt vmcnt(8)" ::: "memory");   // buf0 complete, buf1 in flight
  } else {
    asm volatile("s_waitcnt vmcnt(0)" ::: "memory");
  }
  __builtin_amdgcn_s_barrier();

  for (int it = 0; it < iters; it++) {
    const int cur = it & 1;
#pragma unroll
    for (int ks = 0; ks < 2; ks++) {
      const int swz = ((kc0 + ks * 4) ^ (fr & 7)) * 8;
      f16x8 af[4], bf[4];
#pragma unroll
      for (int i = 0; i < 4; i++) af[i] = *(const f16x8*)&As[cur][(wm + i * 16 + fr) * 64 + swz];
#pragma unroll
      for (int j = 0; j < 4; j++) bf[j] = *(const f16x8*)&Bs[cur][(wn + j * 16 + fr) * 64 + swz];
      __builtin_amdgcn_s_setprio(1);
#pragma unroll
      for (int i = 0; i < 4; i++)
#pragma unroll
        for (int j = 0; j < 4; j++)
          acc[i][j] = __builtin_amdgcn_mfma_f32_16x16x32_f16(af[i], bf[j], acc[i][j], 0, 0, 0);
      __builtin_amdgcn_s_setprio(0);
    }
    asm volatile("s_waitcnt lgkmcnt(0)" ::: "memory");
    __builtin_amdgcn_s_barrier();
    const bool issue = (it + 2 < iters);
    if (issue) stage(cur, (it + 2) * 64);
    if (it + 1 < iters) {
      if (issue) asm volatile("s_waitcnt vmcnt(8)" ::: "memory");
      else       asm volatile("s_waitcnt vmcnt(0)" ::: "memory");
      __builtin_amdgcn_s_barrier();
    }
  }
  float* Pz = P + (((size_t)z * 32 + tile) * 4 + wave) * 4096;
#pragma unroll
  for (int i = 0; i < 4; i++)
#pragma unroll
    for (int j = 0; j < 4; j++)
#pragma unroll
      for (int rr = 0; rr < 4; rr++)
        Pz[((i * 4 + j) * 4 + rr) * 64 + lane] = acc[i][j][rr];
}

// ---- reduce SK blocked partials + bias (+relu), write fp16 or fp32 (128x128 layout) ----
template <bool OUT16, bool RELU, int SK>
__global__ __launch_bounds__(256) void reduce_blocked(const float* __restrict__ P,
                                                      const float* __restrict__ bias,
                                                      void* __restrict__ out,
                                                      int MN, int N) {
  int i4 = (blockIdx.x * 256 + threadIdx.x) * 4;
  if (i4 >= MN) return;
  float4 s = *(const float4*)(P + i4);
#pragma unroll
  for (int z = 1; z < SK; z++) {
    float4 t = *(const float4*)(P + (size_t)z * MN + i4);
    s.x += t.x; s.y += t.y; s.z += t.z; s.w += t.w;
  }
  const int lane0 = i4 & 63;
  const int q     = (i4 >> 6) & 63;
  const int wave  = (i4 >> 12) & 3;
  const int bx    = (i4 >> 14) & 3;
  const int by    = (i4 >> 16) & 7;
  const int rr = q & 3, j_ = (q >> 2) & 3, i_ = q >> 4;
  const int row = bx * 128 + (wave & 1) * 64 + i_ * 16 + (lane0 >> 4) * 4 + rr;
  const int col = by * 128 + (wave >> 1) * 64 + j_ * 16 + (lane0 & 15);
  float4 bv = *(const float4*)(bias + col);
  s.x += bv.x; s.y += bv.y; s.z += bv.z; s.w += bv.w;
  if (RELU) {
    s.x = fmaxf(s.x, 0.0f); s.y = fmaxf(s.y, 0.0f);
    s.z = fmaxf(s.z, 0.0f); s.w = fmaxf(s.w, 0.0f);
  }
  size_t o = (size_t)row * N + col;
  if (OUT16) {
    f16x4 ov;
    ov[0] = (half_t)s.x; ov[1] = (half_t)s.y; ov[2] = (half_t)s.z; ov[3] = (half_t)s.w;
    *(f16x4*)((half_t*)out + o) = ov;
  } else {
    *(float4*)((float*)out + o) = s;
  }
}

// ---- GEMM3 fused: reduce gemm2 partials (z-sum + b2 + relu) inside hs staging,
// then part3[z3][n][147] = h2_tile @ w3^T. Each h2 element is produced by exactly
// one (nb, z3) block -> reduce fusion is traffic-neutral, removes h2 round-trip.
__global__ __launch_bounds__(256) void gemm3_fused(const float* __restrict__ part2,
                                                   const float* __restrict__ b2,
                                                   const float* __restrict__ w3,
                                                   float* __restrict__ part3) {
  __shared__ float hs[8][128];
  const int n0 = blockIdx.x * 8;
  const int z3 = blockIdx.y;
  const int tid = threadIdx.x;
  const int MN = NROI * FC;
  {
    const int idx4 = tid * 4;            // 256 thr x 4 = 1024 elems
    const int nn = idx4 >> 7;
    const int kk = idx4 & 127;
    const int row = n0 + nn;
    const int col = z3 * 128 + kk;
    // invert gemm_lds (128x128) blocked-P layout
    const int bx = (row >> 7) & 3;
    const int by = (col >> 7) & 7;
    const int wv = ((row >> 6) & 1) | (((col >> 6) & 1) << 1);
    const int q  = ((row >> 4) & 3) * 16 + ((col >> 4) & 3) * 4 + (row & 3);
    const int l0 = ((row >> 2) & 3) * 16 + (col & 15);
    const int tile = by * 4 + bx;
    const size_t base = (size_t)((tile * 4 + wv) * 4096 + q * 64 + l0);
    float4 s = *(const float4*)(part2 + base);
#pragma unroll
    for (int z2 = 1; z2 < 8; z2++) {
      float4 t = *(const float4*)(part2 + (size_t)z2 * MN + base);
      s.x += t.x; s.y += t.y; s.z += t.z; s.w += t.w;
    }
    float4 bv = *(const float4*)(b2 + col);
    s.x = fmaxf(s.x + bv.x, 0.0f);
    s.y = fmaxf(s.y + bv.y, 0.0f);
    s.z = fmaxf(s.z + bv.z, 0.0f);
    s.w = fmaxf(s.w + bv.w, 0.0f);
    *(float4*)(&hs[nn][kk]) = s;
  }
  __syncthreads();
  const int j = tid;
  if (j < 147) {
    const float* wr = w3 + (size_t)j * FC + z3 * 128;
    float acc[8] = {0, 0, 0, 0, 0, 0, 0, 0};
    for (int k = 0; k < 128; k += 4) {
      float4 wv = *(const float4*)(wr + k);
#pragma unroll
      for (int nn = 0; nn < 8; nn++)
        acc[nn] += hs[nn][k] * wv.x + hs[nn][k + 1] * wv.y +
                   hs[nn][k + 2] * wv.z + hs[nn][k + 3] * wv.w;
    }
#pragma unroll
    for (int nn = 0; nn < 8; nn++)
      part3[((size_t)z3 * NROI + n0 + nn) * 147 + j] = acc[nn];
  }
}

extern "C" void kernel_launch(void* const* d_in, const int* in_sizes, int n_in,
                              void* d_out, int out_size, void* d_ws, size_t ws_size,
                              hipStream_t stream) {
  const float* feat = (const float*)d_in[0];
  const float* rois = (const float*)d_in[1];
  const float* w1 = (const float*)d_in[2];
  const float* b1 = (const float*)d_in[3];
  const float* w2 = (const float*)d_in[4];
  const float* b2 = (const float*)d_in[5];
  const float* w3 = (const float*)d_in[6];
  const float* b3 = (const float*)d_in[7];
  float* out = (float*)d_out;
  char* ws = (char*)d_ws;

  // workspace carve (~86.1 MB total)
  half_t* featT = (half_t*)ws;                        // 10,240,000 B
  half_t* xh    = (half_t*)(ws + 10240000);           // 12,845,056 B  (k = c*49+p)
  half_t* w1h   = (half_t*)(ws + 23085056);           // 25,690,112 B
  half_t* w2h   = (half_t*)(ws + 48775168);           //  2,097,152 B
  half_t* h1    = (half_t*)(ws + 50872320);           //  1,048,576 B
  float*  part  = (float*)(ws + 54319104);            // 29,360,128 B (gemm1 SK=14 / gemm2 SK=8)
  float*  part3 = (float*)(ws + 83679232);            //  2,408,448 B (gemm3 partials)

  const int MN = NROI * FC;  // 524288

  // transpose + w2 convert (w1 convert overlapped with pool1 below)
  prep0<<<dim3(6032), dim3(256), 0, stream>>>(feat, featT, w2, w2h);

  // pool1 (512 ROI blocks) + w1 convert (6272 streaming blocks) in one launch
  pool_kernel<false><<<dim3(NROI + 6272), dim3(512), 0, stream>>>(
      featT, rois, nullptr, nullptr, xh, nullptr, w1, w1h);

  // GEMM1: (512x12544) @ (1024x12544)^T -> 128x128 tiles, SK=14, 448 blocks, XCD-swizzled
  gemm_lds<14><<<dim3(4, 8, 14), dim3(256), 0, stream>>>(xh, w1h, part, KDIM);
  reduce_blocked<true, true, 14><<<dim3(MN / 1024), dim3(256), 0, stream>>>(part, b1, (void*)h1, MN, FC);

  // GEMM2: (512x1024) @ (1024x1024)^T -> SK=8, 256 blocks, XCD-swizzled
  gemm_lds<8><<<dim3(4, 8, 8), dim3(256), 0, stream>>>(h1, w2h, part, FC);

  // GEMM3 (+fused reduce2): part3 = relu(sum(part)+b2) @ w3^T; z-reduce+b3 folded into pool2
  gemm3_fused<<<dim3(64, 8), dim3(256), 0, stream>>>(part, b2, w3, part3);
  pool_kernel<true><<<dim3(NROI), dim3(512), 0, stream>>>(
      featT, rois, part3, b3, nullptr, out, nullptr, nullptr);
}